// Round 1
// baseline (16.230 us; speedup 1.0000x reference)
//
#include <hip/hip_runtime.h>
#include <hip/hip_bf16.h>
#include <math.h>

#define A_ATOMS 64
#define AEVDIM  384   // 4*16 radial + 10*32 angular

__global__ __launch_bounds__(64) void aev_kernel(
    const int*   __restrict__ species,   // (N, 64)
    const float* __restrict__ coords,    // (N, 64, 3)
    float*       __restrict__ out)       // (N, 64, 384)
{
    constexpr float PI  = 3.14159265358979323846f;
    constexpr float RCR = 5.2f;
    constexpr float RCA = 3.5f;

    const int bid  = blockIdx.x;     // n*64 + i
    const int n    = bid >> 6;
    const int i    = bid & 63;
    const int lane = threadIdx.x;    // 0..63, one wave per block

    __shared__ float sh_aev[AEVDIM];
    __shared__ float s_cx[64], s_cy[64], s_cz[64];
    // compacted angular neighbor list
    __shared__ float s_ux[64], s_uy[64], s_uz[64], s_d[64], s_fc[64];
    __shared__ int   s_nspec[64];

    // zero the accumulator
    for (int f = lane; f < AEVDIM; f += 64) sh_aev[f] = 0.0f;

    // lane owns atom `lane` of molecule n
    const float* cb = coords + (size_t)n * (A_ATOMS * 3);
    const float xj = cb[lane * 3 + 0];
    const float yj = cb[lane * 3 + 1];
    const float zj = cb[lane * 3 + 2];
    const int   sj = species[n * A_ATOMS + lane];
    s_cx[lane] = xj; s_cy[lane] = yj; s_cz[lane] = zj;
    __syncthreads();

    const float xi = s_cx[i], yi = s_cy[i], zi = s_cz[i];
    const float dx = xj - xi, dy = yj - yi, dz = zj - zi;
    const float d  = sqrtf(dx * dx + dy * dy + dz * dz);
    const bool  notself = (lane != i);

    // ---------------- radial: sum_j 0.25*exp(-16*(d-shf)^2)*fc(d) into species bin
    if (notself && d <= RCR) {
        const float fc = 0.5f * cosf(PI * (d * (1.0f / RCR))) + 0.5f;
        const float q  = 0.25f * fc;
        float* dst = &sh_aev[sj * 16];
        #pragma unroll
        for (int r = 0; r < 16; ++r) {
            const float shf = 0.9f + 0.26875f * (float)r;   // 0.9 + (5.2-0.9)/16 * r
            const float t   = d - shf;
            atomicAdd(&dst[r], q * expf(-16.0f * t * t));
        }
    }

    // ---------------- angular: compact neighbors with d <= 3.5
    const bool act = notself && (d <= RCA);
    const unsigned long long bm = __ballot(act);
    const int M = __popcll(bm);
    if (act) {
        const int pos = __popcll(bm & ((1ull << lane) - 1ull));
        const float inv = 1.0f / d;
        s_ux[pos] = dx * inv; s_uy[pos] = dy * inv; s_uz[pos] = dz * inv;
        s_d[pos]  = d;
        s_fc[pos] = 0.5f * cosf(PI * (d * (1.0f / RCA))) + 0.5f;
        s_nspec[pos] = sj;
    }
    __syncthreads();

    // cos/sin of SHF_Z[z] = pi/16*(2z+1)
    const float CZ[8] = { 0.980785280f,  0.831469612f,  0.555570233f,  0.195090322f,
                         -0.195090322f, -0.555570233f, -0.831469612f, -0.980785280f };
    const float SZ[8] = { 0.195090322f,  0.555570233f,  0.831469612f,  0.980785280f,
                          0.980785280f,  0.831469612f,  0.555570233f,  0.195090322f };

    const int nP = (M * (M - 1)) >> 1;   // unordered pairs (term symmetric in j,k)
    for (int p = lane; p < nP; p += 64) {
        // decode p -> (a < b)
        int a = 0, rem = p;
        while (rem >= (M - 1 - a)) { rem -= (M - 1 - a); ++a; }
        const int b = a + 1 + rem;

        const float fp2  = 2.0f * s_fc[a] * s_fc[b];
        const float dot  = s_ux[a] * s_ux[b] + s_uy[a] * s_uy[b] + s_uz[a] * s_uz[b];
        const float ca   = 0.95f * dot;                         // cos(theta), |ca|<=0.95
        const float sa   = sqrtf(fmaxf(0.0f, 1.0f - ca * ca));  // sin(theta) >= 0
        const float davg = 0.5f * (s_d[a] + s_d[b]);

        const int s1 = s_nspec[a], s2 = s_nspec[b];
        const int lo = (s1 < s2) ? s1 : s2;
        const int hi = (s1 < s2) ? s2 : s1;
        const int pb = ((lo * (9 - lo)) >> 1) + (hi - lo);      // packed triu pair index
        float* dst = &sh_aev[64 + pb * 32];

        #pragma unroll
        for (int aa = 0; aa < 4; ++aa) {
            const float shfa = 0.9f + 0.65f * (float)aa;        // 0.9 + (3.5-0.9)/4 * aa
            const float t    = davg - shfa;
            const float base = fp2 * expf(-8.0f * t * t);
            #pragma unroll
            for (int z = 0; z < 8; ++z) {
                // cos(theta - shf_z) via identity; ((1+c)/2)^32 as 5 squarings
                const float c  = ca * CZ[z] + sa * SZ[z];
                float f1 = 0.5f * (1.0f + c);
                f1 = f1 * f1; f1 = f1 * f1; f1 = f1 * f1; f1 = f1 * f1; f1 = f1 * f1;
                atomicAdd(&dst[aa * 8 + z], base * f1);
            }
        }
    }
    __syncthreads();

    // ---------------- write out (n,i) row: 384 floats, coalesced
    float* o = out + (size_t)bid * AEVDIM;
    for (int f = lane; f < AEVDIM; f += 64) o[f] = sh_aev[f];
}

extern "C" void kernel_launch(void* const* d_in, const int* in_sizes, int n_in,
                              void* d_out, int out_size, void* d_ws, size_t ws_size,
                              hipStream_t stream) {
    const int*   species = (const int*)d_in[0];
    const float* coords  = (const float*)d_in[1];
    float*       out     = (float*)d_out;
    const int N = in_sizes[0] / A_ATOMS;   // species is (N, 64)
    aev_kernel<<<N * A_ATOMS, 64, 0, stream>>>(species, coords, out);
}

// Round 2
// 15.197 us; speedup vs baseline: 1.0680x; 1.0680x over previous
//
#include <hip/hip_runtime.h>
#include <hip/hip_bf16.h>
#include <math.h>

#define A_ATOMS 64
#define AEVDIM  384   // 4*16 radial + 10*32 angular

__global__ __launch_bounds__(256) void aev_kernel(
    const int*   __restrict__ species,   // (N, 64)
    const float* __restrict__ coords,    // (N, 64, 3)
    float*       __restrict__ out)       // (N, 64, 384)
{
    constexpr float PI  = 3.14159265358979323846f;
    constexpr float RCR = 5.2f;
    constexpr float RCA = 3.5f;

    const int bid  = blockIdx.x;     // n*64 + i
    const int n    = bid >> 6;
    const int i    = bid & 63;
    const int t    = threadIdx.x;    // 0..255
    const int lane = t & 63;
    const int wid  = t >> 6;         // wave id 0..3

    __shared__ float sh_aev[AEVDIM];
    __shared__ float s_cx[64], s_cy[64], s_cz[64];
    __shared__ int   s_spec[64];
    // compacted angular neighbor list (written by wave 0)
    __shared__ float s_ux[64], s_uy[64], s_uz[64], s_d[64], s_fc[64];
    __shared__ int   s_nspec[64];

    // zero accumulator + stage coords/species in LDS
    for (int f = t; f < AEVDIM; f += 256) sh_aev[f] = 0.0f;
    if (t < 64) {
        const float* cb = coords + (size_t)n * (A_ATOMS * 3) + t * 3;
        s_cx[t] = cb[0]; s_cy[t] = cb[1]; s_cz[t] = cb[2];
        s_spec[t] = species[n * A_ATOMS + t];
    }
    __syncthreads();

    // every wave recomputes all 64 distances (lane = atom j) — removes cross-wave deps
    const float xi = s_cx[i], yi = s_cy[i], zi = s_cz[i];
    const float dx = s_cx[lane] - xi, dy = s_cy[lane] - yi, dz = s_cz[lane] - zi;
    const float d  = sqrtf(dx * dx + dy * dy + dz * dz);
    const bool  notself = (lane != i);
    const int   sj = s_spec[lane];

    // ---------------- radial: wave w handles shifts [4w, 4w+4)
    if (notself && d <= RCR) {
        const float fc = 0.5f * __cosf(PI * (d * (1.0f / RCR))) + 0.5f;
        const float q  = 0.25f * fc;
        float* dst = &sh_aev[sj * 16];
        #pragma unroll
        for (int rr = 0; rr < 4; ++rr) {
            const int   r   = wid * 4 + rr;
            const float shf = 0.9f + 0.26875f * (float)r;   // 0.9 + (5.2-0.9)/16 * r
            const float tt  = d - shf;
            atomicAdd(&dst[r], q * __expf(-16.0f * tt * tt));
        }
    }

    // ---------------- angular neighbor compaction (ballot identical in all waves;
    // wave 0 writes the list, every wave derives the same M)
    const bool act = notself && (d <= RCA);
    const unsigned long long bm = __ballot(act);
    const int M = __popcll(bm);
    if (wid == 0 && act) {
        const int pos = __popcll(bm & ((1ull << lane) - 1ull));
        const float inv = 1.0f / d;
        s_ux[pos] = dx * inv; s_uy[pos] = dy * inv; s_uz[pos] = dz * inv;
        s_d[pos]  = d;
        s_fc[pos] = 0.5f * __cosf(PI * (d * (1.0f / RCA))) + 0.5f;
        s_nspec[pos] = sj;
    }
    __syncthreads();

    // cos/sin of SHF_Z[z] = pi/16*(2z+1)
    const float CZ[8] = { 0.980785280f,  0.831469612f,  0.555570233f,  0.195090322f,
                         -0.195090322f, -0.555570233f, -0.831469612f, -0.980785280f };
    const float SZ[8] = { 0.195090322f,  0.555570233f,  0.831469612f,  0.980785280f,
                          0.980785280f,  0.831469612f,  0.555570233f,  0.195090322f };

    // ---------------- angular: task = (pair, aa-shift); 1 expf + 8-deep atomic chain each
    const int nTask = ((M * (M - 1)) >> 1) << 2;
    for (int task = t; task < nTask; task += 256) {
        const int p  = task >> 2;
        const int aa = task & 3;
        // decode p -> (a < b)
        int a = 0, rem = p;
        while (rem >= (M - 1 - a)) { rem -= (M - 1 - a); ++a; }
        const int b = a + 1 + rem;

        const float fp2  = 2.0f * s_fc[a] * s_fc[b];
        const float dot  = s_ux[a] * s_ux[b] + s_uy[a] * s_uy[b] + s_uz[a] * s_uz[b];
        const float ca   = 0.95f * dot;                         // cos(theta), |ca|<=0.95
        const float sa   = sqrtf(fmaxf(0.0f, 1.0f - ca * ca));  // sin(theta)
        const float davg = 0.5f * (s_d[a] + s_d[b]);

        const int s1 = s_nspec[a], s2 = s_nspec[b];
        const int lo = (s1 < s2) ? s1 : s2;
        const int hi = (s1 < s2) ? s2 : s1;
        const int pb = ((lo * (9 - lo)) >> 1) + (hi - lo);      // packed triu pair index

        const float shfa = 0.9f + 0.65f * (float)aa;            // 0.9 + (3.5-0.9)/4 * aa
        const float tt   = davg - shfa;
        const float base = fp2 * __expf(-8.0f * tt * tt);
        float* dst = &sh_aev[64 + pb * 32 + aa * 8];

        #pragma unroll
        for (int z = 0; z < 8; ++z) {
            // cos(theta - shf_z) via identity; ((1+c)/2)^32 as 5 squarings
            const float c  = ca * CZ[z] + sa * SZ[z];
            float f1 = 0.5f * (1.0f + c);
            f1 = f1 * f1; f1 = f1 * f1; f1 = f1 * f1; f1 = f1 * f1; f1 = f1 * f1;
            atomicAdd(&dst[z], base * f1);
        }
    }
    __syncthreads();

    // ---------------- write out (n,i) row: 384 floats, coalesced
    float* o = out + (size_t)bid * AEVDIM;
    for (int f = t; f < AEVDIM; f += 256) o[f] = sh_aev[f];
}

extern "C" void kernel_launch(void* const* d_in, const int* in_sizes, int n_in,
                              void* d_out, int out_size, void* d_ws, size_t ws_size,
                              hipStream_t stream) {
    const int*   species = (const int*)d_in[0];
    const float* coords  = (const float*)d_in[1];
    float*       out     = (float*)d_out;
    const int N = in_sizes[0] / A_ATOMS;   // species is (N, 64)
    aev_kernel<<<N * A_ATOMS, 256, 0, stream>>>(species, coords, out);
}